// Round 1
// baseline (287.531 us; speedup 1.0000x reference)
//
#include <hip/hip_runtime.h>
#include <math.h>

#define NUM_HEADS 16
#define HEAD_DIM 64

typedef __bf16 bf16x8 __attribute__((ext_vector_type(8)));
typedef float floatx4 __attribute__((ext_vector_type(4)));

__device__ __forceinline__ unsigned short f2b(float f) {
  unsigned int u = __float_as_uint(f);
  u += 0x7fffu + ((u >> 16) & 1u);
  return (unsigned short)(u >> 16);
}
__device__ __forceinline__ float b2f(unsigned short s) {
  return __uint_as_float(((unsigned int)s) << 16);
}

__device__ __forceinline__ void async16(const void* g, void* l) {
  __builtin_amdgcn_global_load_lds(
      (const __attribute__((address_space(1))) unsigned int*)g,
      (__attribute__((address_space(3))) unsigned int*)l, 16, 0, 0);
}

// ---------------- fp32 -> bf16 convert ----------------
__global__ void cvt_f32_bf16(const float* __restrict__ in,
                             unsigned short* __restrict__ out, int n4) {
  int i = blockIdx.x * 256 + threadIdx.x;
  if (i < n4) {
    float4 v = ((const float4*)in)[i];
    ushort4 o;
    o.x = f2b(v.x); o.y = f2b(v.y); o.z = f2b(v.z); o.w = f2b(v.w);
    ((ushort4*)out)[i] = o;
  }
}

// ---------------- RoPE (in place, bf16, (B,H,S,HD) layout) ----------------
__global__ void rope_kernel(unsigned short* Q, unsigned short* K,
                            const int* __restrict__ pos, int S, int total) {
  int tid = blockIdx.x * 256 + threadIdx.x;
  if (tid >= total) return;
  unsigned short* buf = (blockIdx.y == 0) ? Q : K;
  int i = tid & 31;            // pair index within head dim (0..31)
  int rest = tid >> 5;
  int s = rest % S;
  int bh = rest / S;
  // inv_freq = 10000^(-i/32) = exp(-i * ln(10000)/32)
  float inv = expf(-0.28782313662425575f * (float)i);
  float ang = (float)pos[s] * inv;
  float sn, cs;
  sincosf(ang, &sn, &cs);      // precise: |ang| up to ~2047 rad
  size_t base = ((size_t)bh * S + s) * HEAD_DIM + 2 * i;
  float x1 = b2f(buf[base]);
  float x2 = b2f(buf[base + 1]);
  buf[base]     = f2b(x1 * cs - x2 * sn);
  buf[base + 1] = f2b(x1 * sn + x2 * cs);
}

// ---------------- bf16 GEMM, C = A * B^T ----------------
// A: (M,K) row-major bf16. B: (N,K) row-major bf16.
// MODE 0: out bf16 scattered into (B,H,S,HD) layout (QKV). blockIdx.z picks B/out.
// MODE 1: out fp32 row-major (M,N).
template <int MODE>
__global__ __launch_bounds__(256, 2)
void gemm_bt(const unsigned short* __restrict__ A,
             const unsigned short* __restrict__ B0,
             const unsigned short* __restrict__ B1,
             const unsigned short* __restrict__ B2,
             void* out0v, void* out1v, void* out2v,
             int M, int N, int K, int S) {
  __shared__ unsigned short As[128 * 32];
  __shared__ unsigned short Bs[128 * 32];
  const int tid = threadIdx.x;
  const int lane = tid & 63;
  const int w = tid >> 6;
  const int lane16 = lane & 15;
  const int g = lane >> 4;
  const int wm = w >> 1, wn = w & 1;
  const int m0 = blockIdx.y * 128;
  const int n0 = blockIdx.x * 128;
  const unsigned short* Bp = (blockIdx.z == 0) ? B0 : (blockIdx.z == 1 ? B1 : B2);

  const floatx4 vzero = {0.f, 0.f, 0.f, 0.f};
  floatx4 acc[4][4];
#pragma unroll
  for (int i = 0; i < 4; i++)
#pragma unroll
    for (int j = 0; j < 4; j++) acc[i][j] = vzero;

  const int ar = lane >> 2;        // row within 16-row chunk
  const int ac = (lane & 3) * 8;   // col (elements)

  for (int k0 = 0; k0 < K; k0 += 32) {
#pragma unroll
    for (int c = 0; c < 2; c++) {
      int chunk = w * 2 + c;       // 0..7, wave-uniform
      async16(A  + (size_t)(m0 + chunk * 16 + ar) * K + k0 + ac, As + chunk * 512);
      async16(Bp + (size_t)(n0 + chunk * 16 + ar) * K + k0 + ac, Bs + chunk * 512);
    }
    __syncthreads();
    bf16x8 a[4], b[4];
#pragma unroll
    for (int mt = 0; mt < 4; mt++)
      a[mt] = *(const bf16x8*)&As[(wm * 64 + mt * 16 + lane16) * 32 + g * 8];
#pragma unroll
    for (int nt = 0; nt < 4; nt++)
      b[nt] = *(const bf16x8*)&Bs[(wn * 64 + nt * 16 + lane16) * 32 + g * 8];
#pragma unroll
    for (int mt = 0; mt < 4; mt++)
#pragma unroll
      for (int nt = 0; nt < 4; nt++)
        acc[mt][nt] = __builtin_amdgcn_mfma_f32_16x16x32_bf16(a[mt], b[nt], acc[mt][nt], 0, 0, 0);
    __syncthreads();
  }

  if (MODE == 0) {
    unsigned short* outp = (unsigned short*)((blockIdx.z == 0) ? out0v
                              : (blockIdx.z == 1 ? out1v : out2v));
#pragma unroll
    for (int mt = 0; mt < 4; mt++) {
#pragma unroll
      for (int r = 0; r < 4; r++) {
        int m = m0 + wm * 64 + mt * 16 + g * 4 + r;
        int bb = m / S, s = m - bb * S;
#pragma unroll
        for (int nt = 0; nt < 4; nt++) {
          int n = n0 + wn * 64 + nt * 16 + lane16;
          int h = n >> 6, dl = n & 63;
          outp[(((size_t)(bb * NUM_HEADS + h) * S + s) << 6) + dl] = f2b(acc[mt][nt][r]);
        }
      }
    }
  } else {
    float* outp = (float*)out0v;
#pragma unroll
    for (int mt = 0; mt < 4; mt++) {
#pragma unroll
      for (int r = 0; r < 4; r++) {
        int m = m0 + wm * 64 + mt * 16 + g * 4 + r;
#pragma unroll
        for (int nt = 0; nt < 4; nt++) {
          int n = n0 + wn * 64 + nt * 16 + lane16;
          outp[(size_t)m * N + n] = acc[mt][nt][r];
        }
      }
    }
  }
}

// ---------------- causal flash attention ----------------
// Q,K,V: (B*H, S, 64) bf16 (RoPE already applied to Q,K). Out: (B*S, 1024) bf16.
__global__ __launch_bounds__(256, 2)
void flash_attn(const unsigned short* __restrict__ Q,
                const unsigned short* __restrict__ Kv,
                const unsigned short* __restrict__ Vv,
                unsigned short* __restrict__ Oattn, int S) {
  __shared__ unsigned short Ks[64 * 72];   // K tile, row-major, pad 72
  __shared__ unsigned short Vt[64 * 72];   // V tile transposed: Vt[d][j]
  __shared__ unsigned short Ps[4 * 16 * 72]; // per-wave P tiles
  const int tid = threadIdx.x;
  const int lane = tid & 63;
  const int w = tid >> 6;
  const int lane16 = lane & 15;
  const int g = lane >> 4;
  const int qt = blockIdx.x;
  const int bh = blockIdx.y;
  const size_t headbase = (size_t)bh * S * HEAD_DIM;

  bf16x8 qf[2];
  {
    int qrow = qt * 64 + w * 16 + lane16;
    const unsigned short* qp = Q + headbase + (size_t)qrow * HEAD_DIM + g * 8;
    qf[0] = *(const bf16x8*)qp;
    qf[1] = *(const bf16x8*)(qp + 32);
  }
  const floatx4 vzero = {0.f, 0.f, 0.f, 0.f};
  floatx4 oacc[4];
  float m_i[4], l_i[4];
#pragma unroll
  for (int i = 0; i < 4; i++) { oacc[i] = vzero; m_i[i] = -INFINITY; l_i[i] = 0.f; }

  unsigned short* Pw = Ps + w * 16 * 72;

  for (int t = 0; t <= qt; t++) {
    // stage K tile (coalesced, 16B per lane)
#pragma unroll
    for (int c = 0; c < 2; c++) {
      int idx = c * 256 + tid;
      int row = idx >> 3, ch = idx & 7;
      *(uint4*)&Ks[row * 72 + ch * 8] =
          *(const uint4*)&Kv[headbase + (size_t)(t * 64 + row) * HEAD_DIM + ch * 8];
    }
    // stage V transposed (scalar LDS writes, 2-way banked)
#pragma unroll
    for (int c = 0; c < 2; c++) {
      int ch = c * 4 + w;
      union { uint4 v; unsigned short u[8]; } vb;
      vb.v = *(const uint4*)&Vv[headbase + (size_t)(t * 64 + lane) * HEAD_DIM + ch * 8];
#pragma unroll
      for (int e = 0; e < 8; e++) Vt[(ch * 8 + e) * 72 + lane] = vb.u[e];
    }
    __syncthreads();

    // scores: S = Q * K^T  (16x64 per wave)
    floatx4 sc[4];
#pragma unroll
    for (int nt = 0; nt < 4; nt++) {
      sc[nt] = vzero;
      bf16x8 b0 = *(const bf16x8*)&Ks[(nt * 16 + lane16) * 72 + g * 8];
      bf16x8 b1 = *(const bf16x8*)&Ks[(nt * 16 + lane16) * 72 + 32 + g * 8];
      sc[nt] = __builtin_amdgcn_mfma_f32_16x16x32_bf16(qf[0], b0, sc[nt], 0, 0, 0);
      sc[nt] = __builtin_amdgcn_mfma_f32_16x16x32_bf16(qf[1], b1, sc[nt], 0, 0, 0);
    }
    // scale + causal mask (diagonal tile only)
#pragma unroll
    for (int nt = 0; nt < 4; nt++)
#pragma unroll
      for (int r = 0; r < 4; r++) {
        float v = sc[nt][r] * 0.125f;
        if (t == qt) {
          int jg = t * 64 + nt * 16 + lane16;
          int ig = qt * 64 + w * 16 + g * 4 + r;
          if (jg > ig) v = -INFINITY;
        }
        sc[nt][r] = v;
      }
    // online softmax
    float al[4];
#pragma unroll
    for (int r = 0; r < 4; r++) {
      float m = fmaxf(fmaxf(sc[0][r], sc[1][r]), fmaxf(sc[2][r], sc[3][r]));
      m = fmaxf(m, __shfl_xor(m, 1, 16));
      m = fmaxf(m, __shfl_xor(m, 2, 16));
      m = fmaxf(m, __shfl_xor(m, 4, 16));
      m = fmaxf(m, __shfl_xor(m, 8, 16));
      float mn = fmaxf(m_i[r], m);
      al[r] = __expf(m_i[r] - mn);
      m_i[r] = mn;
    }
    float rs[4] = {0.f, 0.f, 0.f, 0.f};
#pragma unroll
    for (int nt = 0; nt < 4; nt++)
#pragma unroll
      for (int r = 0; r < 4; r++) {
        float p = __expf(sc[nt][r] - m_i[r]);
        rs[r] += p;
        Pw[(g * 4 + r) * 72 + nt * 16 + lane16] = f2b(p);
      }
#pragma unroll
    for (int r = 0; r < 4; r++) {
      float t2 = rs[r];
      t2 += __shfl_xor(t2, 1, 16);
      t2 += __shfl_xor(t2, 2, 16);
      t2 += __shfl_xor(t2, 4, 16);
      t2 += __shfl_xor(t2, 8, 16);
      l_i[r] = l_i[r] * al[r] + t2;
#pragma unroll
      for (int nt = 0; nt < 4; nt++) oacc[nt][r] *= al[r];
    }
    // O += P * V
    bf16x8 pa0 = *(const bf16x8*)&Pw[lane16 * 72 + g * 8];
    bf16x8 pa1 = *(const bf16x8*)&Pw[lane16 * 72 + 32 + g * 8];
#pragma unroll
    for (int nt = 0; nt < 4; nt++) {
      bf16x8 b0 = *(const bf16x8*)&Vt[(nt * 16 + lane16) * 72 + g * 8];
      bf16x8 b1 = *(const bf16x8*)&Vt[(nt * 16 + lane16) * 72 + 32 + g * 8];
      oacc[nt] = __builtin_amdgcn_mfma_f32_16x16x32_bf16(pa0, b0, oacc[nt], 0, 0, 0);
      oacc[nt] = __builtin_amdgcn_mfma_f32_16x16x32_bf16(pa1, b1, oacc[nt], 0, 0, 0);
    }
    __syncthreads();
  }
  // epilogue: O / l, scatter into (B*S, D) with d = h*64+dl
  int b = bh >> 4, h = bh & 15;
#pragma unroll
  for (int r = 0; r < 4; r++) {
    float invl = 1.0f / l_i[r];
    int s = qt * 64 + w * 16 + g * 4 + r;
    size_t rowb = ((size_t)b * S + s) * 1024 + h * 64;
#pragma unroll
    for (int nt = 0; nt < 4; nt++)
      Oattn[rowb + nt * 16 + lane16] = f2b(oacc[nt][r] * invl);
  }
}

// ---------------- launcher ----------------
extern "C" void kernel_launch(void* const* d_in, const int* in_sizes, int n_in,
                              void* d_out, int out_size, void* d_ws, size_t ws_size,
                              hipStream_t stream) {
  const float* x  = (const float*)d_in[0];
  const int*  pos = (const int*)d_in[1];
  const float* wq = (const float*)d_in[2];
  const float* wk = (const float*)d_in[3];
  const float* wv = (const float*)d_in[4];
  const float* wo = (const float*)d_in[5];

  const int D = 1024;
  const int S = in_sizes[1];
  const int M = in_sizes[0] / D;       // B*S
  const int B = M / S;
  const int BH = B * NUM_HEADS;

  char* wsb = (char*)d_ws;
  size_t off = 0;
  auto alloc = [&](size_t bytes) {
    char* p = wsb + off;
    off += (bytes + 255) & ~(size_t)255;
    return p;
  };
  unsigned short* Xb   = (unsigned short*)alloc((size_t)M * D * 2);
  unsigned short* Wqb  = (unsigned short*)alloc((size_t)D * D * 2);
  unsigned short* Wkb  = (unsigned short*)alloc((size_t)D * D * 2);
  unsigned short* Wvb  = (unsigned short*)alloc((size_t)D * D * 2);
  unsigned short* Wob  = (unsigned short*)alloc((size_t)D * D * 2);
  unsigned short* Qb   = (unsigned short*)alloc((size_t)M * D * 2);
  unsigned short* Kb   = (unsigned short*)alloc((size_t)M * D * 2);
  unsigned short* Vb   = (unsigned short*)alloc((size_t)M * D * 2);
  unsigned short* Attn = (unsigned short*)alloc((size_t)M * D * 2);
  (void)ws_size;

  // converts
  {
    int n4 = M * D / 4;
    cvt_f32_bf16<<<dim3((n4 + 255) / 256), 256, 0, stream>>>(x, Xb, n4);
    int w4 = D * D / 4;
    cvt_f32_bf16<<<dim3((w4 + 255) / 256), 256, 0, stream>>>(wq, Wqb, w4);
    cvt_f32_bf16<<<dim3((w4 + 255) / 256), 256, 0, stream>>>(wk, Wkb, w4);
    cvt_f32_bf16<<<dim3((w4 + 255) / 256), 256, 0, stream>>>(wv, Wvb, w4);
    cvt_f32_bf16<<<dim3((w4 + 255) / 256), 256, 0, stream>>>(wo, Wob, w4);
  }
  // QKV projections -> (B,H,S,HD) bf16
  gemm_bt<0><<<dim3(D / 128, M / 128, 3), 256, 0, stream>>>(
      Xb, Wqb, Wkb, Wvb, Qb, Kb, Vb, M, D, D, S);
  // RoPE on Q and K
  {
    int total = BH * S * 32;
    rope_kernel<<<dim3((total + 255) / 256, 2), 256, 0, stream>>>(Qb, Kb, pos, S, total);
  }
  // causal flash attention -> (B*S, D) bf16
  flash_attn<<<dim3(S / 64, BH), 256, 0, stream>>>(Qb, Kb, Vb, Attn, S);
  // output projection -> fp32 d_out
  gemm_bt<1><<<dim3(D / 128, M / 128, 1), 256, 0, stream>>>(
      Attn, Wob, Wob, Wob, d_out, d_out, d_out, M, D, D, S);
}